// Round 2
// baseline (586.353 us; speedup 1.0000x reference)
//
#include <hip/hip_runtime.h>
#include <hip/hip_bf16.h>
#include <stdint.h>

// Problem constants (from reference): H=16 heads, D=1024, DK=512, Dh=64,
// Lq=2048, B=4, Lk=1024. All inputs fp32; outputs: out (Lq,B,D) then coverage (B,Lq,Lk), fp32.
#define H_  16
#define D_  1024
#define DK_ 512
#define DH_ 64
#define LQ_ 2048
#define B_  4
#define LK_ 1024

typedef __attribute__((ext_vector_type(8))) short bf16x8_t;   // 8 bf16 (4 VGPRs) MFMA operand
typedef __attribute__((ext_vector_type(4))) unsigned short us4_t;
typedef __attribute__((ext_vector_type(4))) float fx4_t;
typedef __attribute__((ext_vector_type(4))) int ix4_t;

__device__ __forceinline__ unsigned short f2bf(float f) {
  unsigned int u = __builtin_bit_cast(unsigned int, f);
  u += 0x7fffu + ((u >> 16) & 1u);           // RNE
  return (unsigned short)(u >> 16);
}
__device__ __forceinline__ float bf2f(unsigned short h) {
  unsigned int u = ((unsigned int)h) << 16;
  return __builtin_bit_cast(float, u);
}

// ---------- cast f32 -> bf16 with scale (8 elems/thread, vectorized) ----------
__global__ __launch_bounds__(256) void cast_scale_k(const float* __restrict__ in,
    unsigned short* __restrict__ out, int n, float scale) {
  int i = (blockIdx.x * 256 + threadIdx.x) * 8;
  if (i >= n) return;
  fx4_t a = *(const fx4_t*)(in + i);
  fx4_t b = *(const fx4_t*)(in + i + 4);
  unsigned short o[8];
  o[0] = f2bf(a[0] * scale); o[1] = f2bf(a[1] * scale);
  o[2] = f2bf(a[2] * scale); o[3] = f2bf(a[3] * scale);
  o[4] = f2bf(b[0] * scale); o[5] = f2bf(b[1] * scale);
  o[6] = f2bf(b[2] * scale); o[7] = f2bf(b[3] * scale);
  *(us4_t*)(out + i)     = *(us4_t*)&o[0];
  *(us4_t*)(out + i + 4) = *(us4_t*)&o[4];
}

// ---------- weight transpose-cast: in (K,N) f32 -> out (N,K) bf16 ----------
__global__ __launch_bounds__(256) void wtrans_k(const float* __restrict__ in,
    unsigned short* __restrict__ out, int K, int N) {
  __shared__ float tile[32][33];
  int t = threadIdx.x;
  int n0 = blockIdx.x * 32, k0 = blockIdx.y * 32;
  int r = t >> 3, c = (t & 7) * 4;
  fx4_t v = *(const fx4_t*)(in + (size_t)(k0 + r) * N + n0 + c);
  tile[r][c] = v[0]; tile[r][c + 1] = v[1]; tile[r][c + 2] = v[2]; tile[r][c + 3] = v[3];
  __syncthreads();
  us4_t o;
  o[0] = f2bf(tile[c + 0][r]); o[1] = f2bf(tile[c + 1][r]);
  o[2] = f2bf(tile[c + 2][r]); o[3] = f2bf(tile[c + 3][r]);
  *(us4_t*)(out + (size_t)(n0 + r) * K + k0 + c) = o;
}

// ---------- GEMM: C(M,N) = A(M,K) x Bt(N,K)^T, bf16 in, bf16 or f32 out ----------
// 128x128 tile, BK=32, 4 waves (each 64x64 = 4x4 16x16 fragments), reg-staged LDS.
template<int OUT_BF16>
__global__ __launch_bounds__(256) void gemm_bt_k(const unsigned short* __restrict__ A,
    const unsigned short* __restrict__ Bt, void* __restrict__ C, int M, int N, int K) {
  __shared__ unsigned short Alds[128 * 32];
  __shared__ unsigned short Blds[128 * 32];
  int t = threadIdx.x;
  int l = t & 63, w = t >> 6;
  int g = l >> 4, qi = l & 15;
  int wr = w >> 1, wc = w & 1;
  int m0 = blockIdx.x * 128, n0 = blockIdx.y * 128;
  int arow = t >> 2, acol = (t & 3) * 8;
  fx4_t acc[4][4] = {};
  for (int kb = 0; kb < K; kb += 32) {
    *(bf16x8_t*)&Alds[arow * 32 + acol]        = *(const bf16x8_t*)&A[(size_t)(m0 + arow) * K + kb + acol];
    *(bf16x8_t*)&Alds[(arow + 64) * 32 + acol] = *(const bf16x8_t*)&A[(size_t)(m0 + arow + 64) * K + kb + acol];
    *(bf16x8_t*)&Blds[arow * 32 + acol]        = *(const bf16x8_t*)&Bt[(size_t)(n0 + arow) * K + kb + acol];
    *(bf16x8_t*)&Blds[(arow + 64) * 32 + acol] = *(const bf16x8_t*)&Bt[(size_t)(n0 + arow + 64) * K + kb + acol];
    __syncthreads();
    bf16x8_t af[4], bfr[4];
#pragma unroll
    for (int mi = 0; mi < 4; ++mi) af[mi] = *(bf16x8_t*)&Alds[(wr * 64 + mi * 16 + qi) * 32 + g * 8];
#pragma unroll
    for (int ni = 0; ni < 4; ++ni) bfr[ni] = *(bf16x8_t*)&Blds[(wc * 64 + ni * 16 + qi) * 32 + g * 8];
#pragma unroll
    for (int mi = 0; mi < 4; ++mi)
#pragma unroll
      for (int ni = 0; ni < 4; ++ni)
        acc[mi][ni] = __builtin_amdgcn_mfma_f32_16x16x32_bf16(af[mi], bfr[ni], acc[mi][ni], 0, 0, 0);
    __syncthreads();
  }
#pragma unroll
  for (int mi = 0; mi < 4; ++mi)
#pragma unroll
    for (int ni = 0; ni < 4; ++ni) {
      int row = m0 + wr * 64 + mi * 16 + g * 4;      // C/D: row=(lane>>4)*4+reg
      int col = n0 + wc * 64 + ni * 16 + qi;         //       col=lane&15
#pragma unroll
      for (int r = 0; r < 4; ++r) {
        if (OUT_BF16) ((unsigned short*)C)[(size_t)(row + r) * N + col] = f2bf(acc[mi][ni][r]);
        else          ((float*)C)[(size_t)(row + r) * N + col] = acc[mi][ni][r];
      }
    }
}

// ---------- V transpose: vb (Lk*B, D) bf16 -> vbT[(b*D + n)*Lk + lk] ----------
__global__ __launch_bounds__(256) void vtrans_k(const unsigned short* __restrict__ vb,
    unsigned short* __restrict__ vbT) {
  __shared__ unsigned short tile[64][72];   // 72: keeps 16B store alignment (144B rows)
  int t = threadIdx.x;
  int lk0 = blockIdx.x * 64, n0 = blockIdx.y * 64, b = blockIdx.z;
  int i = t >> 2, c = (t & 3) * 16;
  const unsigned short* src = &vb[((size_t)(lk0 + i) * B_ + b) * D_ + n0 + c];
  *(bf16x8_t*)&tile[i][c]     = *(const bf16x8_t*)src;
  *(bf16x8_t*)&tile[i][c + 8] = *(const bf16x8_t*)(src + 8);
  __syncthreads();
  unsigned short o[16];
#pragma unroll
  for (int u = 0; u < 16; ++u) o[u] = tile[c + u][i];
  unsigned short* dst = &vbT[((size_t)b * D_ + n0 + i) * LK_ + lk0 + c];
  *(bf16x8_t*)&dst[0] = *(bf16x8_t*)&o[0];
  *(bf16x8_t*)&dst[8] = *(bf16x8_t*)&o[8];
}

// ---------- fused attention + coverage ----------
// Block = (b, 16 q-rows). 16 waves = 16 heads. Swapped QK^T (mfma(K,Q)) so each lane's
// S^T values are {k = kt*32+kh*16+4g+r, q = q0+qi}. Two passes over k: A computes (m,l),
// B recomputes S, accumulates coverage (bf16, LDS) and O via PV MFMA. Head-rotated
// k-tiles + per-step barrier => race-free coverage accumulation without atomics.
// MASK ARRIVES AS INT32 WORDS (harness maps bool -> const int*), one word per element.
__global__ __launch_bounds__(1024) void attn_k(const unsigned short* __restrict__ qb,
    const unsigned short* __restrict__ kb, const unsigned short* __restrict__ vbT,
    const int* __restrict__ mask, unsigned short* __restrict__ outp,
    float* __restrict__ cov) {
  __shared__ unsigned short covl[16 * 1032];      // bf16 coverage accum, padded stride
  __shared__ unsigned short plds[16 * 16 * 40];   // per-wave P staging (16 rows x 40, pad for banks)
  int bid = blockIdx.x;
  int x = bid & 7;                      // XCD swizzle: XCD x -> batch x>>1 (K/V L2 locality)
  int b = x >> 1;
  int qt = ((bid >> 3) << 1) | (x & 1);
  int q0 = qt * 16;
  int t = threadIdx.x;
  int h = t >> 6, l = t & 63;
  int g = l >> 4, qi = l & 15;
  for (int i = t; i < 16 * 1032; i += 1024) covl[i] = 0;

  int q = q0 + qi;
  const unsigned short* qrow = qb + ((size_t)q * B_ + b) * D_ + h * DH_;
  bf16x8_t qf0 = *(const bf16x8_t*)(qrow + g * 8);        // d in [g*8, g*8+8)
  bf16x8_t qf1 = *(const bf16x8_t*)(qrow + 32 + g * 8);   // d in [32+g*8, ...)
  const unsigned short* kbase = kb + (size_t)b * D_ + h * DH_;
  const int* mrow = mask + ((size_t)b * LQ_ + q) * LK_;
  const unsigned short* vbase = vbT + ((size_t)(b * H_ + h) * DH_) * LK_;
  unsigned short* myp = plds + h * (16 * 40);

  float m_l = -1e30f, l_l = 0.f;
  float s[8];
  // ---- pass A: online (m, l) per q row (scores already in log2e units via Q scale) ----
  for (int kt = 0; kt < 32; ++kt) {
#pragma unroll
    for (int kh = 0; kh < 2; ++kh) {
      int lk = kt * 32 + kh * 16 + qi;
      const unsigned short* kr = kbase + (size_t)lk * (B_ * D_);
      bf16x8_t kf0 = *(const bf16x8_t*)(kr + g * 8);
      bf16x8_t kf1 = *(const bf16x8_t*)(kr + 32 + g * 8);
      fx4_t acc = {0.f, 0.f, 0.f, 0.f};
      acc = __builtin_amdgcn_mfma_f32_16x16x32_bf16(kf0, qf0, acc, 0, 0, 0);
      acc = __builtin_amdgcn_mfma_f32_16x16x32_bf16(kf1, qf1, acc, 0, 0, 0);
      ix4_t mk = *(const ix4_t*)(mrow + kt * 32 + kh * 16 + g * 4);
#pragma unroll
      for (int r = 0; r < 4; ++r)
        s[kh * 4 + r] = mk[r] ? -1e30f : acc[r];
    }
    float vmax = s[0];
#pragma unroll
    for (int i = 1; i < 8; ++i) vmax = fmaxf(vmax, s[i]);
    float mn = fmaxf(m_l, vmax);
    float add = 0.f;
#pragma unroll
    for (int i = 0; i < 8; ++i) add += exp2f(s[i] - mn);
    l_l = l_l * exp2f(m_l - mn) + add;
    m_l = mn;
  }
  // cross-group (lanes qi, qi+16, qi+32, qi+48) combine
#pragma unroll
  for (int off = 16; off <= 32; off <<= 1) {
    float mo = __shfl_xor(m_l, off);
    float lo = __shfl_xor(l_l, off);
    float mn = fmaxf(m_l, mo);
    l_l = l_l * exp2f(m_l - mn) + lo * exp2f(mo - mn);
    m_l = mn;
  }
  float inv_l = 1.0f / l_l;
  float c_scale = inv_l * (1.0f / 16.0f);   // 1/(l*H) for coverage
  float inv_r[4];
#pragma unroll
  for (int r = 0; r < 4; ++r) inv_r[r] = __shfl(inv_l, g * 4 + r);  // l for O rows 4g+r

  fx4_t o_acc[4] = {};
  __syncthreads();   // covl zeroed before pass B
  // ---- pass B: P, coverage, PV ----
  for (int tt = 0; tt < 32; ++tt) {
    int kt = (tt + 2 * h) & 31;   // rotation: waves hit disjoint k-tiles each step
#pragma unroll
    for (int kh = 0; kh < 2; ++kh) {
      int lk = kt * 32 + kh * 16 + qi;
      const unsigned short* kr = kbase + (size_t)lk * (B_ * D_);
      bf16x8_t kf0 = *(const bf16x8_t*)(kr + g * 8);
      bf16x8_t kf1 = *(const bf16x8_t*)(kr + 32 + g * 8);
      fx4_t acc = {0.f, 0.f, 0.f, 0.f};
      acc = __builtin_amdgcn_mfma_f32_16x16x32_bf16(kf0, qf0, acc, 0, 0, 0);
      acc = __builtin_amdgcn_mfma_f32_16x16x32_bf16(kf1, qf1, acc, 0, 0, 0);
      ix4_t mk = *(const ix4_t*)(mrow + kt * 32 + kh * 16 + g * 4);
      float p[4];
#pragma unroll
      for (int r = 0; r < 4; ++r) {
        float sv = mk[r] ? -1e30f : acc[r];
        p[r] = exp2f(sv - m_l);
      }
      // coverage accumulate (bf16 RMW; exclusive tile per wave this step)
      unsigned short* cp = &covl[qi * 1032 + kt * 32 + kh * 16 + g * 4];
#pragma unroll
      for (int r = 0; r < 4; ++r) cp[r] = f2bf(bf2f(cp[r]) + p[r] * c_scale);
      // P -> LDS in row-major [q][k_local] so PV A-frag is one ds_read_b128
      unsigned short pw[4];
#pragma unroll
      for (int r = 0; r < 4; ++r) pw[r] = f2bf(p[r]);
      *(us4_t*)&myp[qi * 40 + kh * 16 + g * 4] = *(us4_t*)&pw[0];
    }
    asm volatile("s_waitcnt lgkmcnt(0)" ::: "memory");
    __builtin_amdgcn_sched_barrier(0);
    bf16x8_t pa = *(bf16x8_t*)&myp[qi * 40 + g * 8];
#pragma unroll
    for (int f = 0; f < 4; ++f) {
      bf16x8_t vf = *(const bf16x8_t*)(vbase + (size_t)(f * 16 + qi) * LK_ + kt * 32 + g * 8);
      o_acc[f] = __builtin_amdgcn_mfma_f32_16x16x32_bf16(pa, vf, o_acc[f], 0, 0, 0);
    }
    __syncthreads();
  }
  // ---- O write (normalized) ----
#pragma unroll
  for (int f = 0; f < 4; ++f)
#pragma unroll
    for (int r = 0; r < 4; ++r) {
      int lq = q0 + g * 4 + r;
      outp[((size_t)lq * B_ + b) * D_ + h * DH_ + f * 16 + qi] = f2bf(o_acc[f][r] * inv_r[r]);
    }
  __syncthreads();
  // ---- coverage write (f32) ----
  {
    int row = t >> 6;
    int k0 = (t & 63) * 16;
    const unsigned short* src = &covl[row * 1032 + k0];
    float* dst = &cov[((size_t)b * LQ_ + q0 + row) * LK_ + k0];
#pragma unroll
    for (int u = 0; u < 16; u += 4) {
      fx4_t ov = { bf2f(src[u]), bf2f(src[u + 1]), bf2f(src[u + 2]), bf2f(src[u + 3]) };
      *(fx4_t*)(dst + u) = ov;
    }
  }
}

extern "C" void kernel_launch(void* const* d_in, const int* in_sizes, int n_in,
                              void* d_out, int out_size, void* d_ws, size_t ws_size,
                              hipStream_t stream) {
  (void)in_sizes; (void)n_in; (void)out_size; (void)ws_size;
  const float* query = (const float*)d_in[0];
  const float* key   = (const float*)d_in[1];
  // d_in[2] (value) is intentionally unused: reference projects `key` for both K and V.
  const int* mask = (const int*)d_in[3];   // jnp.bool_ -> harness integer convention -> int32 words
  const float* Wq = (const float*)d_in[4];
  const float* Wk = (const float*)d_in[5];
  const float* Wv = (const float*)d_in[6];
  const float* Wc = (const float*)d_in[7];
  float* out = (float*)d_out;
  float* cov = out + (size_t)LQ_ * B_ * D_;

  char* p = (char*)d_ws;
  unsigned short* queryb = (unsigned short*)p; p += (size_t)LQ_ * B_ * D_ * 2;
  unsigned short* keyb   = (unsigned short*)p; p += (size_t)LK_ * B_ * DK_ * 2;
  unsigned short* WqT    = (unsigned short*)p; p += (size_t)D_ * D_ * 2;
  unsigned short* WkT    = (unsigned short*)p; p += (size_t)D_ * DK_ * 2;
  unsigned short* WvT    = (unsigned short*)p; p += (size_t)D_ * DK_ * 2;
  unsigned short* WcT    = (unsigned short*)p; p += (size_t)D_ * D_ * 2;
  unsigned short* qbuf   = (unsigned short*)p; p += (size_t)LQ_ * B_ * D_ * 2;
  unsigned short* kbuf   = (unsigned short*)p; p += (size_t)LK_ * B_ * D_ * 2;
  unsigned short* vbuf   = (unsigned short*)p; p += (size_t)LK_ * B_ * D_ * 2;
  unsigned short* vbT    = (unsigned short*)p; p += (size_t)LK_ * B_ * D_ * 2;
  unsigned short* outp   = queryb;   // reuse: queryb dead after Q projection

  // fold softmax scale (1/sqrt(Dh)=1/8) and log2(e) into Q so softmax uses exp2 directly
  const float QSCALE = 0.125f * 1.44269504088896340736f;

  cast_scale_k<<<dim3((LQ_ * B_ * D_) / 2048), 256, 0, stream>>>(query, queryb, LQ_ * B_ * D_, QSCALE);
  cast_scale_k<<<dim3((LK_ * B_ * DK_) / 2048), 256, 0, stream>>>(key, keyb, LK_ * B_ * DK_, 1.0f);
  wtrans_k<<<dim3(D_ / 32, D_ / 32), 256, 0, stream>>>(Wq, WqT, D_, D_);
  wtrans_k<<<dim3(D_ / 32, DK_ / 32), 256, 0, stream>>>(Wk, WkT, DK_, D_);
  wtrans_k<<<dim3(D_ / 32, DK_ / 32), 256, 0, stream>>>(Wv, WvT, DK_, D_);
  wtrans_k<<<dim3(D_ / 32, D_ / 32), 256, 0, stream>>>(Wc, WcT, D_, D_);
  gemm_bt_k<1><<<dim3(LQ_ * B_ / 128, D_ / 128), 256, 0, stream>>>(queryb, WqT, qbuf, LQ_ * B_, D_, D_);
  gemm_bt_k<1><<<dim3(LK_ * B_ / 128, D_ / 128), 256, 0, stream>>>(keyb, WkT, kbuf, LK_ * B_, D_, DK_);
  gemm_bt_k<1><<<dim3(LK_ * B_ / 128, D_ / 128), 256, 0, stream>>>(keyb, WvT, vbuf, LK_ * B_, D_, DK_);
  vtrans_k<<<dim3(LK_ / 64, D_ / 64, B_), 256, 0, stream>>>(vbuf, vbT);
  attn_k<<<dim3(B_ * (LQ_ / 16)), 1024, 0, stream>>>(qbuf, kbuf, vbT, mask, outp, cov);
  gemm_bt_k<0><<<dim3(LQ_ * B_ / 128, D_ / 128), 256, 0, stream>>>(outp, WcT, out, LQ_ * B_, D_, D_);
}